// Round 3
// baseline (559.177 us; speedup 1.0000x reference)
//
#include <hip/hip_runtime.h>
#include <math.h>

#define BN 256
#define BLOCK 512

__device__ __forceinline__ float wred_sum(float v) {
#pragma unroll
  for (int m = 32; m >= 1; m >>= 1) v += __shfl_xor(v, m, 64);
  return v;
}

// 4 interleaved 64-lane butterflies (ILP-4 on the shfl chain)
__device__ __forceinline__ void wred_sum4(float& a, float& b, float& c, float& d) {
#pragma unroll
  for (int m = 32; m >= 1; m >>= 1) {
    a += __shfl_xor(a, m, 64);
    b += __shfl_xor(b, m, 64);
    c += __shfl_xor(c, m, 64);
    d += __shfl_xor(d, m, 64);
  }
}

template<int P, int Q>
__device__ __forceinline__ void jrot(float K[3][3], float V[3][3]) {
  float apq = K[P][Q];
  if (apq == 0.f) return;
  float app = K[P][P], aqq = K[Q][Q];
  float tau = (aqq - app) / (2.f * apq);
  float st = sqrtf(1.f + tau * tau);
  float tt = (tau >= 0.f) ? 1.f / (tau + st) : 1.f / (tau - st);
  float c = 1.f / sqrtf(1.f + tt * tt);
  float s = tt * c;
#pragma unroll
  for (int k = 0; k < 3; k++) { float kp = K[k][P], kq = K[k][Q]; K[k][P] = c * kp - s * kq; K[k][Q] = s * kp + c * kq; }
#pragma unroll
  for (int k = 0; k < 3; k++) { float kp = K[P][k], kq = K[Q][k]; K[P][k] = c * kp - s * kq; K[Q][k] = s * kp + c * kq; }
#pragma unroll
  for (int k = 0; k < 3; k++) { float vp = V[k][P], vq = V[k][Q]; V[k][P] = c * vp - s * vq; V[k][Q] = s * vp + c * vq; }
}

template<int A, int C>
__device__ __forceinline__ void cswap(float lam[3], float V[3][3]) {
  if (lam[A] < lam[C]) {
    float tl = lam[A]; lam[A] = lam[C]; lam[C] = tl;
#pragma unroll
    for (int k = 0; k < 3; k++) { float tv = V[k][A]; V[k][A] = V[k][C]; V[k][C] = tv; }
  }
}

extern "C" __global__ void __launch_bounds__(BLOCK, 4)
svdhead_kernel(const float* __restrict__ src,
               const float* __restrict__ tgt,
               const float* __restrict__ scores,
               const int* __restrict__ idx0,
               float* __restrict__ out)
{
  __shared__ __align__(16) float Af[6][BN];   // [0..2]=count*kpts1_d, [3..5]=kpts1_d
  __shared__ float kx[3][BN];                 // kpts0
  __shared__ float vmaskS[BN];
  __shared__ int cnt[BN];
  __shared__ float bacc[31];  // 0..8 P_v, 9..17 P_f, 18..20 Sc, 21..23 Scf, 24..26 Sxv, 27..29 Sxf, 30 M

  const int t = threadIdx.x;
  const int b = blockIdx.x;
  const int lane = t & 63;
  const int wave = t >> 6;

  if (t < 31) bacc[t] = 0.f;
  if (t < BN) cnt[t] = 0;
  __syncthreads();

  float x0 = 0.f, x1 = 0.f, x2 = 0.f, vf = 0.f;
  if (t < BN) {
    int id = idx0[(size_t)b * BN + t];        // values in [0,256]; 256 == SENTINEL
    int valid = ((unsigned)id < 256u);
    vf = valid ? 1.f : 0.f;
    if (valid) atomicAdd(&cnt[id], 1);
    const float* sb = src + (size_t)b * 3 * BN;
    const float* tb = tgt + (size_t)b * 3 * BN;
    x0 = sb[t]; x1 = sb[BN + t]; x2 = sb[2 * BN + t];
    kx[0][t] = x0; kx[1][t] = x1; kx[2][t] = x2;
    vmaskS[t] = vf;
    Af[3][t] = tb[t]; Af[4][t] = tb[BN + t]; Af[5][t] = tb[2 * BN + t];
  }
  {
    float r0 = wred_sum(vf);
    float r1 = wred_sum(vf * x0);
    float r2 = wred_sum(vf * x1);
    float r3 = wred_sum(vf * x2);
    float r4 = wred_sum(x0);
    float r5 = wred_sum(x1);
    float r6 = wred_sum(x2);
    if (lane == 0) {
      atomicAdd(&bacc[30], r0);
      atomicAdd(&bacc[24], r1); atomicAdd(&bacc[25], r2); atomicAdd(&bacc[26], r3);
      atomicAdd(&bacc[27], r4); atomicAdd(&bacc[28], r5); atomicAdd(&bacc[29], r6);
    }
  }
  __syncthreads();
  if (t < BN) {
    float cf = (float)cnt[t];
    Af[0][t] = cf * Af[3][t];
    Af[1][t] = cf * Af[4][t];
    Af[2][t] = cf * Af[5][t];
  }
  __syncthreads();

  const int j0 = lane * 4;
  float4 a6[6];
#pragma unroll
  for (int k = 0; k < 6; k++) a6[k] = *(const float4*)&Af[k][j0];

  float acc[24];
#pragma unroll
  for (int k = 0; k < 24; k++) acc[k] = 0.f;

  const float* srow = scores + (size_t)b * BN * BN;
  const int pbase = wave * 32;                 // 32 rows per wave, 4 per group
  const float* wbase = srow + (size_t)pbase * BN + j0;

  float4 cur[4];
#pragma unroll
  for (int r = 0; r < 4; r++) cur[r] = *(const float4*)(wbase + (size_t)r * BN);

#pragma unroll
  for (int g = 0; g < 8; g++) {
    float4 nx[4];
    if (g < 7) {
#pragma unroll
      for (int r = 0; r < 4; r++)
        nx[r] = *(const float4*)(wbase + (size_t)(4 * (g + 1) + r) * BN);
    }
    // exponentials (in place)
    float4 ex[4];
#pragma unroll
    for (int r = 0; r < 4; r++) {
      ex[r].x = __expf(cur[r].x); ex[r].y = __expf(cur[r].y);
      ex[r].z = __expf(cur[r].z); ex[r].w = __expf(cur[r].w);
    }
    float s0 = (ex[0].x + ex[0].y) + (ex[0].z + ex[0].w);
    float s1 = (ex[1].x + ex[1].y) + (ex[1].z + ex[1].w);
    float s2 = (ex[2].x + ex[2].y) + (ex[2].z + ex[2].w);
    float s3 = (ex[3].x + ex[3].y) + (ex[3].z + ex[3].w);
    wred_sum4(s0, s1, s2, s3);
    float invs[4];
    invs[0] = __builtin_amdgcn_rcpf(s0);
    invs[1] = __builtin_amdgcn_rcpf(s1);
    invs[2] = __builtin_amdgcn_rcpf(s2);
    invs[3] = __builtin_amdgcn_rcpf(s3);
#pragma unroll
    for (int r = 0; r < 4; r++) {
      int p = pbase + g * 4 + r;
      float inv = invs[r];
      float pd[6];
#pragma unroll
      for (int k = 0; k < 6; k++)
        pd[k] = ex[r].x * a6[k].x + ex[r].y * a6[k].y + ex[r].z * a6[k].z + ex[r].w * a6[k].w;
      float pvf = vmaskS[p];
      float g0 = kx[0][p], g1 = kx[1][p], g2 = kx[2][p];
      float gv = pvf * inv;
      acc[18] += gv * pd[0]; acc[19] += gv * pd[1]; acc[20] += gv * pd[2];
      acc[21] += inv * pd[3]; acc[22] += inv * pd[4]; acc[23] += inv * pd[5];
      float a0 = gv * g0, a1 = gv * g1, a2 = gv * g2;
      float f0 = inv * g0, f1 = inv * g1, f2 = inv * g2;
      acc[0] += a0 * pd[0]; acc[1] += a0 * pd[1]; acc[2] += a0 * pd[2];
      acc[3] += a1 * pd[0]; acc[4] += a1 * pd[1]; acc[5] += a1 * pd[2];
      acc[6] += a2 * pd[0]; acc[7] += a2 * pd[1]; acc[8] += a2 * pd[2];
      acc[9]  += f0 * pd[3]; acc[10] += f0 * pd[4]; acc[11] += f0 * pd[5];
      acc[12] += f1 * pd[3]; acc[13] += f1 * pd[4]; acc[14] += f1 * pd[5];
      acc[15] += f2 * pd[3]; acc[16] += f2 * pd[4]; acc[17] += f2 * pd[5];
    }
#pragma unroll
    for (int r = 0; r < 4; r++) cur[r] = nx[r];
  }
#pragma unroll
  for (int k = 0; k < 24; k++) {
    float r = wred_sum(acc[k]);
    if (lane == 0) atomicAdd(&bacc[k], r);
  }
  __syncthreads();

  if (t == 0) {
    float M = bacc[30];
    float Minv = 1.f / fmaxf(M, 1.f);
    bool use_v = (M > 3.f);
    const float Ninv = 1.f / (float)BN;
    float H[3][3], mu[3];
#pragma unroll
    for (int d = 0; d < 3; d++) {
      mu[d] = use_v ? bacc[24 + d] * Minv : bacc[27 + d] * Ninv;
#pragma unroll
      for (int e = 0; e < 3; e++) {
        float hv = bacc[d * 3 + e]     - bacc[24 + d] * bacc[18 + e] * Minv;
        float hf = bacc[9 + d * 3 + e] - bacc[27 + d] * bacc[21 + e] * Ninv;
        H[d][e] = use_v ? hv : hf;
      }
    }
    float K[3][3];
#pragma unroll
    for (int i = 0; i < 3; i++)
#pragma unroll
      for (int j = 0; j < 3; j++) {
        float s_ = 0.f;
#pragma unroll
        for (int k = 0; k < 3; k++) s_ += H[k][i] * H[k][j];
        K[i][j] = s_;
      }
    float V[3][3] = {{1.f,0.f,0.f},{0.f,1.f,0.f},{0.f,0.f,1.f}};
    for (int sw = 0; sw < 8; sw++) { jrot<0,1>(K, V); jrot<0,2>(K, V); jrot<1,2>(K, V); }
    float lam[3] = {K[0][0], K[1][1], K[2][2]};
    cswap<0,1>(lam, V); cswap<1,2>(lam, V); cswap<0,1>(lam, V);

    float v1[3] = {V[0][0], V[1][0], V[2][0]};
    float v2[3] = {V[0][1], V[1][1], V[2][1]};
    float v3[3] = {V[0][2], V[1][2], V[2][2]};
    float u1[3], u2[3], u3[3];
#pragma unroll
    for (int i = 0; i < 3; i++) {
      u1[i] = H[i][0] * v1[0] + H[i][1] * v1[1] + H[i][2] * v1[2];
      u2[i] = H[i][0] * v2[0] + H[i][1] * v2[1] + H[i][2] * v2[2];
    }
    float n1s = u1[0]*u1[0] + u1[1]*u1[1] + u1[2]*u1[2];
    if (n1s > 1e-24f) { float r = 1.f / sqrtf(n1s); u1[0]*=r; u1[1]*=r; u1[2]*=r; }
    else { u1[0] = 1.f; u1[1] = 0.f; u1[2] = 0.f; }
    float d12 = u1[0]*u2[0] + u1[1]*u2[1] + u1[2]*u2[2];
    u2[0] -= d12 * u1[0]; u2[1] -= d12 * u1[1]; u2[2] -= d12 * u1[2];
    float n2s = u2[0]*u2[0] + u2[1]*u2[1] + u2[2]*u2[2];
    if (n2s > 1e-24f) { float r = 1.f / sqrtf(n2s); u2[0]*=r; u2[1]*=r; u2[2]*=r; }
    else {
      float ex = (fabsf(u1[0]) < 0.9f) ? 1.f : 0.f;
      float ey = 1.f - ex;
      float cx = u1[1]*0.f - u1[2]*ey;
      float cy = u1[2]*ex - u1[0]*0.f;
      float cz = u1[0]*ey - u1[1]*ex;
      float nn = 1.f / sqrtf(cx*cx + cy*cy + cz*cz + 1e-30f);
      u2[0] = cx*nn; u2[1] = cy*nn; u2[2] = cz*nn;
    }
    u3[0] = u1[1]*u2[2] - u1[2]*u2[1];
    u3[1] = u1[2]*u2[0] - u1[0]*u2[2];
    u3[2] = u1[0]*u2[1] - u1[1]*u2[0];
    float detV = v1[0]*(v2[1]*v3[2] - v2[2]*v3[1])
               - v1[1]*(v2[0]*v3[2] - v2[2]*v3[0])
               + v1[2]*(v2[0]*v3[1] - v2[1]*v3[0]);
    float f = (detV < 0.f) ? -1.f : 1.f;
    float R_[3][3];
#pragma unroll
    for (int i = 0; i < 3; i++)
#pragma unroll
      for (int k = 0; k < 3; k++)
        R_[i][k] = v1[i]*u1[k] + v2[i]*u2[k] + f * v3[i]*u3[k];

    float* Rout = out + (size_t)b * 9;
#pragma unroll
    for (int i = 0; i < 3; i++)
#pragma unroll
      for (int k = 0; k < 3; k++)
        Rout[i * 3 + k] = R_[i][k];
    float* Tout = out + (size_t)gridDim.x * 9 + (size_t)b * 3;
#pragma unroll
    for (int i = 0; i < 3; i++)
      Tout[i] = -(R_[i][0]*mu[0] + R_[i][1]*mu[1] + R_[i][2]*mu[2]);
  }
}

extern "C" void kernel_launch(void* const* d_in, const int* in_sizes, int n_in,
                              void* d_out, int out_size, void* d_ws, size_t ws_size,
                              hipStream_t stream) {
  const float* src = (const float*)d_in[0];
  const float* tgt = (const float*)d_in[1];
  const float* scores = (const float*)d_in[2];
  const int* idx0 = (const int*)d_in[3];
  float* out = (float*)d_out;
  int B = in_sizes[0] / (3 * BN);
  hipLaunchKernelGGL(svdhead_kernel, dim3(B), dim3(BLOCK), 0, stream,
                     src, tgt, scores, idx0, out);
}

// Round 5
// 139.588 us; speedup vs baseline: 4.0059x; 4.0059x over previous
//
#include <hip/hip_runtime.h>
#include <math.h>

#define BN 256
#define BLOCK 512

__device__ __forceinline__ float wred_sum(float v) {
#pragma unroll
  for (int m = 32; m >= 1; m >>= 1) v += __shfl_xor(v, m, 64);
  return v;
}

// 4 interleaved 64-lane butterflies (ILP-4 on the shfl chain)
__device__ __forceinline__ void wred_sum4(float& a, float& b, float& c, float& d) {
#pragma unroll
  for (int m = 32; m >= 1; m >>= 1) {
    a += __shfl_xor(a, m, 64);
    b += __shfl_xor(b, m, 64);
    c += __shfl_xor(c, m, 64);
    d += __shfl_xor(d, m, 64);
  }
}

template<int P, int Q>
__device__ __forceinline__ void jrot(float K[3][3], float V[3][3]) {
  float apq = K[P][Q];
  if (apq == 0.f) return;
  float app = K[P][P], aqq = K[Q][Q];
  float tau = (aqq - app) / (2.f * apq);
  float st = sqrtf(1.f + tau * tau);
  float tt = (tau >= 0.f) ? 1.f / (tau + st) : 1.f / (tau - st);
  float c = 1.f / sqrtf(1.f + tt * tt);
  float s = tt * c;
#pragma unroll
  for (int k = 0; k < 3; k++) { float kp = K[k][P], kq = K[k][Q]; K[k][P] = c * kp - s * kq; K[k][Q] = s * kp + c * kq; }
#pragma unroll
  for (int k = 0; k < 3; k++) { float kp = K[P][k], kq = K[Q][k]; K[P][k] = c * kp - s * kq; K[Q][k] = s * kp + c * kq; }
#pragma unroll
  for (int k = 0; k < 3; k++) { float vp = V[k][P], vq = V[k][Q]; V[k][P] = c * vp - s * vq; V[k][Q] = s * vp + c * vq; }
}

template<int A, int C>
__device__ __forceinline__ void cswap(float lam[3], float V[3][3]) {
  if (lam[A] < lam[C]) {
    float tl = lam[A]; lam[A] = lam[C]; lam[C] = tl;
#pragma unroll
    for (int k = 0; k < 3; k++) { float tv = V[k][A]; V[k][A] = V[k][C]; V[k][C] = tv; }
  }
}

__device__ __forceinline__ void acc4(float4& T, float s, const float4& e) {
  T.x += s * e.x; T.y += s * e.y; T.z += s * e.z; T.w += s * e.w;
}

__device__ __forceinline__ float dot4(const float4& a, const float4& b) {
  return a.x * b.x + a.y * b.y + a.z * b.z + a.w * b.w;
}

extern "C" __global__ void __launch_bounds__(BLOCK, 2)
svdhead_kernel(const float* __restrict__ src,
               const float* __restrict__ tgt,
               const float* __restrict__ scores,
               const int* __restrict__ idx0,
               float* __restrict__ out)
{
  __shared__ __align__(16) float Af[6][BN];   // [0..2]=count*kpts1_d, [3..5]=kpts1_d
  __shared__ float kx[3][BN];                 // kpts0
  __shared__ float vmaskS[BN];
  __shared__ int cnt[BN];
  __shared__ float bacc[31];  // 0..8 P_v, 9..17 P_f, 18..20 Sc, 21..23 Scf, 24..26 Sxv, 27..29 Sxf, 30 M

  const int t = threadIdx.x;
  const int b = blockIdx.x;
  const int lane = t & 63;
  const int wave = t >> 6;

  if (t < 31) bacc[t] = 0.f;
  if (t < BN) cnt[t] = 0;
  __syncthreads();

  float x0 = 0.f, x1 = 0.f, x2 = 0.f, vf = 0.f;
  if (t < BN) {
    int id = idx0[(size_t)b * BN + t];        // values in [0,256]; 256 == SENTINEL
    int valid = ((unsigned)id < 256u);
    vf = valid ? 1.f : 0.f;
    if (valid) atomicAdd(&cnt[id], 1);
    const float* sb = src + (size_t)b * 3 * BN;
    const float* tb = tgt + (size_t)b * 3 * BN;
    x0 = sb[t]; x1 = sb[BN + t]; x2 = sb[2 * BN + t];
    kx[0][t] = x0; kx[1][t] = x1; kx[2][t] = x2;
    vmaskS[t] = vf;
    Af[3][t] = tb[t]; Af[4][t] = tb[BN + t]; Af[5][t] = tb[2 * BN + t];
  }
  {
    float r0 = wred_sum(vf);
    float r1 = wred_sum(vf * x0);
    float r2 = wred_sum(vf * x1);
    float r3 = wred_sum(vf * x2);
    float r4 = wred_sum(x0);
    float r5 = wred_sum(x1);
    float r6 = wred_sum(x2);
    if (lane == 0) {
      atomicAdd(&bacc[30], r0);
      atomicAdd(&bacc[24], r1); atomicAdd(&bacc[25], r2); atomicAdd(&bacc[26], r3);
      atomicAdd(&bacc[27], r4); atomicAdd(&bacc[28], r5); atomicAdd(&bacc[29], r6);
    }
  }
  __syncthreads();
  if (t < BN) {
    float cf = (float)cnt[t];
    Af[0][t] = cf * Af[3][t];
    Af[1][t] = cf * Af[4][t];
    Af[2][t] = cf * Af[5][t];
  }
  __syncthreads();

  const int j0 = lane * 4;
  const float* srow = scores + (size_t)b * BN * BN;
  const int pbase = wave * 32;                 // 32 rows per wave, 4 per group
  const float* wbase = srow + (size_t)pbase * BN + j0;

  // per-lane column accumulators: Tv_d[j] = sum_p (vf*inv*x_d)(p) * E[p][j]
  //                               Tf_d[j] = sum_p (inv*x_d)(p)    * E[p][j]
  float4 Tv0 = {0,0,0,0}, Tv1 = {0,0,0,0}, Tv2 = {0,0,0,0}, Tv3 = {0,0,0,0};
  float4 Tf0 = {0,0,0,0}, Tf1 = {0,0,0,0}, Tf2 = {0,0,0,0}, Tf3 = {0,0,0,0};

  float4 cur[4];
#pragma unroll
  for (int r = 0; r < 4; r++) cur[r] = *(const float4*)(wbase + (size_t)r * BN);

#pragma unroll
  for (int g = 0; g < 8; g++) {
    float4 nx[4];
    if (g < 7) {
#pragma unroll
      for (int r = 0; r < 4; r++)
        nx[r] = *(const float4*)(wbase + (size_t)(4 * (g + 1) + r) * BN);
    }
    float4 ex[4];
#pragma unroll
    for (int r = 0; r < 4; r++) {
      ex[r].x = __expf(cur[r].x); ex[r].y = __expf(cur[r].y);
      ex[r].z = __expf(cur[r].z); ex[r].w = __expf(cur[r].w);
    }
    float s0 = (ex[0].x + ex[0].y) + (ex[0].z + ex[0].w);
    float s1 = (ex[1].x + ex[1].y) + (ex[1].z + ex[1].w);
    float s2 = (ex[2].x + ex[2].y) + (ex[2].z + ex[2].w);
    float s3 = (ex[3].x + ex[3].y) + (ex[3].z + ex[3].w);
    wred_sum4(s0, s1, s2, s3);
    float invs[4];
    invs[0] = __builtin_amdgcn_rcpf(s0);
    invs[1] = __builtin_amdgcn_rcpf(s1);
    invs[2] = __builtin_amdgcn_rcpf(s2);
    invs[3] = __builtin_amdgcn_rcpf(s3);
#pragma unroll
    for (int r = 0; r < 4; r++) {
      int p = pbase + g * 4 + r;
      float inv = invs[r];
      float pvf = vmaskS[p];
      float g0 = kx[0][p], g1 = kx[1][p], g2 = kx[2][p];
      float wf1 = inv * g0, wf2 = inv * g1, wf3 = inv * g2;
      float wv0 = pvf * inv;
      float wv1 = pvf * wf1, wv2 = pvf * wf2, wv3 = pvf * wf3;
      acc4(Tf0, inv, ex[r]);
      acc4(Tf1, wf1, ex[r]);
      acc4(Tf2, wf2, ex[r]);
      acc4(Tf3, wf3, ex[r]);
      acc4(Tv0, wv0, ex[r]);
      acc4(Tv1, wv1, ex[r]);
      acc4(Tv2, wv2, ex[r]);
      acc4(Tv3, wv3, ex[r]);
    }
#pragma unroll
    for (int r = 0; r < 4; r++) cur[r] = nx[r];
  }

  // epilogue dots: contract T accumulators with the A columns this lane owns
  float acc[24];
  {
    float4 a6[6];
#pragma unroll
    for (int k = 0; k < 6; k++) a6[k] = *(const float4*)&Af[k][j0];
#pragma unroll
    for (int e = 0; e < 3; e++) {
      acc[0 + e]  = dot4(Tv1, a6[e]);      // P_v row d=0
      acc[3 + e]  = dot4(Tv2, a6[e]);      // P_v row d=1
      acc[6 + e]  = dot4(Tv3, a6[e]);      // P_v row d=2
      acc[9 + e]  = dot4(Tf1, a6[3 + e]);  // P_f row d=0
      acc[12 + e] = dot4(Tf2, a6[3 + e]);  // P_f row d=1
      acc[15 + e] = dot4(Tf3, a6[3 + e]);  // P_f row d=2
      acc[18 + e] = dot4(Tv0, a6[e]);      // Sc
      acc[21 + e] = dot4(Tf0, a6[3 + e]);  // Scf
    }
  }
#pragma unroll
  for (int k = 0; k < 24; k++) {
    float r = wred_sum(acc[k]);
    if (lane == 0) atomicAdd(&bacc[k], r);
  }
  __syncthreads();

  if (t == 0) {
    float M = bacc[30];
    float Minv = 1.f / fmaxf(M, 1.f);
    bool use_v = (M > 3.f);
    const float Ninv = 1.f / (float)BN;
    float H[3][3], mu[3];
#pragma unroll
    for (int d = 0; d < 3; d++) {
      mu[d] = use_v ? bacc[24 + d] * Minv : bacc[27 + d] * Ninv;
#pragma unroll
      for (int e = 0; e < 3; e++) {
        float hv = bacc[d * 3 + e]     - bacc[24 + d] * bacc[18 + e] * Minv;
        float hf = bacc[9 + d * 3 + e] - bacc[27 + d] * bacc[21 + e] * Ninv;
        H[d][e] = use_v ? hv : hf;
      }
    }
    float K[3][3];
#pragma unroll
    for (int i = 0; i < 3; i++)
#pragma unroll
      for (int j = 0; j < 3; j++) {
        float s_ = 0.f;
#pragma unroll
        for (int k = 0; k < 3; k++) s_ += H[k][i] * H[k][j];
        K[i][j] = s_;
      }
    float V[3][3] = {{1.f,0.f,0.f},{0.f,1.f,0.f},{0.f,0.f,1.f}};
    for (int sw = 0; sw < 8; sw++) { jrot<0,1>(K, V); jrot<0,2>(K, V); jrot<1,2>(K, V); }
    float lam[3] = {K[0][0], K[1][1], K[2][2]};
    cswap<0,1>(lam, V); cswap<1,2>(lam, V); cswap<0,1>(lam, V);

    float v1[3] = {V[0][0], V[1][0], V[2][0]};
    float v2[3] = {V[0][1], V[1][1], V[2][1]};
    float v3[3] = {V[0][2], V[1][2], V[2][2]};
    float u1[3], u2[3], u3[3];
#pragma unroll
    for (int i = 0; i < 3; i++) {
      u1[i] = H[i][0] * v1[0] + H[i][1] * v1[1] + H[i][2] * v1[2];
      u2[i] = H[i][0] * v2[0] + H[i][1] * v2[1] + H[i][2] * v2[2];
    }
    float n1s = u1[0]*u1[0] + u1[1]*u1[1] + u1[2]*u1[2];
    if (n1s > 1e-24f) { float r = 1.f / sqrtf(n1s); u1[0]*=r; u1[1]*=r; u1[2]*=r; }
    else { u1[0] = 1.f; u1[1] = 0.f; u1[2] = 0.f; }
    float d12 = u1[0]*u2[0] + u1[1]*u2[1] + u1[2]*u2[2];
    u2[0] -= d12 * u1[0]; u2[1] -= d12 * u1[1]; u2[2] -= d12 * u1[2];
    float n2s = u2[0]*u2[0] + u2[1]*u2[1] + u2[2]*u2[2];
    if (n2s > 1e-24f) { float r = 1.f / sqrtf(n2s); u2[0]*=r; u2[1]*=r; u2[2]*=r; }
    else {
      float ex_ = (fabsf(u1[0]) < 0.9f) ? 1.f : 0.f;
      float ey = 1.f - ex_;
      float cx = u1[1]*0.f - u1[2]*ey;
      float cy = u1[2]*ex_ - u1[0]*0.f;
      float cz = u1[0]*ey - u1[1]*ex_;
      float nn = 1.f / sqrtf(cx*cx + cy*cy + cz*cz + 1e-30f);
      u2[0] = cx*nn; u2[1] = cy*nn; u2[2] = cz*nn;
    }
    u3[0] = u1[1]*u2[2] - u1[2]*u2[1];
    u3[1] = u1[2]*u2[0] - u1[0]*u2[2];
    u3[2] = u1[0]*u2[1] - u1[1]*u2[0];
    float detV = v1[0]*(v2[1]*v3[2] - v2[2]*v3[1])
               - v1[1]*(v2[0]*v3[2] - v2[2]*v3[0])
               + v1[2]*(v2[0]*v3[1] - v2[1]*v3[0]);
    float f = (detV < 0.f) ? -1.f : 1.f;
    float R_[3][3];
#pragma unroll
    for (int i = 0; i < 3; i++)
#pragma unroll
      for (int k = 0; k < 3; k++)
        R_[i][k] = v1[i]*u1[k] + v2[i]*u2[k] + f * v3[i]*u3[k];

    float* Rout = out + (size_t)b * 9;
#pragma unroll
    for (int i = 0; i < 3; i++)
#pragma unroll
      for (int k = 0; k < 3; k++)
        Rout[i * 3 + k] = R_[i][k];
    float* Tout = out + (size_t)gridDim.x * 9 + (size_t)b * 3;
#pragma unroll
    for (int i = 0; i < 3; i++)
      Tout[i] = -(R_[i][0]*mu[0] + R_[i][1]*mu[1] + R_[i][2]*mu[2]);
  }
}

extern "C" void kernel_launch(void* const* d_in, const int* in_sizes, int n_in,
                              void* d_out, int out_size, void* d_ws, size_t ws_size,
                              hipStream_t stream) {
  const float* src = (const float*)d_in[0];
  const float* tgt = (const float*)d_in[1];
  const float* scores = (const float*)d_in[2];
  const int* idx0 = (const int*)d_in[3];
  float* out = (float*)d_out;
  int B = in_sizes[0] / (3 * BN);
  hipLaunchKernelGGL(svdhead_kernel, dim3(B), dim3(BLOCK), 0, stream,
                     src, tgt, scores, idx0, out);
}

// Round 6
// 56.127 us; speedup vs baseline: 9.9627x; 2.4870x over previous
//
#include <hip/hip_runtime.h>
#include <math.h>

#define BN 256
#define BLOCK 512

__device__ __forceinline__ float wred_sum(float v) {
#pragma unroll
  for (int m = 32; m >= 1; m >>= 1) v += __shfl_xor(v, m, 64);
  return v;
}

// 2 interleaved 64-lane butterflies (ILP-2 on the shfl chain)
__device__ __forceinline__ void wred_sum2(float& a, float& b) {
#pragma unroll
  for (int m = 32; m >= 1; m >>= 1) {
    a += __shfl_xor(a, m, 64);
    b += __shfl_xor(b, m, 64);
  }
}

template<int P, int Q>
__device__ __forceinline__ void jrot(float K[3][3], float V[3][3]) {
  float apq = K[P][Q];
  if (apq == 0.f) return;
  float app = K[P][P], aqq = K[Q][Q];
  float tau = (aqq - app) / (2.f * apq);
  float st = sqrtf(1.f + tau * tau);
  float tt = (tau >= 0.f) ? 1.f / (tau + st) : 1.f / (tau - st);
  float c = 1.f / sqrtf(1.f + tt * tt);
  float s = tt * c;
#pragma unroll
  for (int k = 0; k < 3; k++) { float kp = K[k][P], kq = K[k][Q]; K[k][P] = c * kp - s * kq; K[k][Q] = s * kp + c * kq; }
#pragma unroll
  for (int k = 0; k < 3; k++) { float kp = K[P][k], kq = K[Q][k]; K[P][k] = c * kp - s * kq; K[Q][k] = s * kp + c * kq; }
#pragma unroll
  for (int k = 0; k < 3; k++) { float vp = V[k][P], vq = V[k][Q]; V[k][P] = c * vp - s * vq; V[k][Q] = s * vp + c * vq; }
}

template<int A, int C>
__device__ __forceinline__ void cswap(float lam[3], float V[3][3]) {
  if (lam[A] < lam[C]) {
    float tl = lam[A]; lam[A] = lam[C]; lam[C] = tl;
#pragma unroll
    for (int k = 0; k < 3; k++) { float tv = V[k][A]; V[k][A] = V[k][C]; V[k][C] = tv; }
  }
}

__device__ __forceinline__ void acc4(float4& T, float s, const float4& e) {
  T.x += s * e.x; T.y += s * e.y; T.z += s * e.z; T.w += s * e.w;
}

__device__ __forceinline__ float dot4(const float4& a, const float4& b) {
  return a.x * b.x + a.y * b.y + a.z * b.z + a.w * b.w;
}

extern "C" __global__ void __launch_bounds__(BLOCK, 2)
svdhead_kernel(const float* __restrict__ src,
               const float* __restrict__ tgt,
               const float* __restrict__ scores,
               const int* __restrict__ idx0,
               float* __restrict__ out)
{
  __shared__ __align__(16) float Af[6][BN];   // [0..2]=count*kpts1_d, [3..5]=kpts1_d
  __shared__ __align__(16) float kxv[BN][4];  // {x0, x1, x2, vf} per row
  __shared__ int cnt[BN];
  __shared__ float bacc[31];  // 0..8 P_v, 9..17 P_f, 18..20 Sc, 21..23 Scf, 24..26 Sxv, 27..29 Sxf, 30 M

  const int t = threadIdx.x;
  const int b = blockIdx.x;
  const int lane = t & 63;
  const int wave = t >> 6;

  if (t < 31) bacc[t] = 0.f;
  if (t < BN) cnt[t] = 0;
  __syncthreads();

  float x0 = 0.f, x1 = 0.f, x2 = 0.f, vf = 0.f;
  if (t < BN) {
    int id = idx0[(size_t)b * BN + t];        // values in [0,256]; 256 == SENTINEL
    int valid = ((unsigned)id < 256u);
    vf = valid ? 1.f : 0.f;
    if (valid) atomicAdd(&cnt[id], 1);
    const float* sb = src + (size_t)b * 3 * BN;
    const float* tb = tgt + (size_t)b * 3 * BN;
    x0 = sb[t]; x1 = sb[BN + t]; x2 = sb[2 * BN + t];
    kxv[t][0] = x0; kxv[t][1] = x1; kxv[t][2] = x2; kxv[t][3] = vf;
    Af[3][t] = tb[t]; Af[4][t] = tb[BN + t]; Af[5][t] = tb[2 * BN + t];
  }
  {
    float r0 = wred_sum(vf);
    float r1 = wred_sum(vf * x0);
    float r2 = wred_sum(vf * x1);
    float r3 = wred_sum(vf * x2);
    float r4 = wred_sum(x0);
    float r5 = wred_sum(x1);
    float r6 = wred_sum(x2);
    if (lane == 0) {
      atomicAdd(&bacc[30], r0);
      atomicAdd(&bacc[24], r1); atomicAdd(&bacc[25], r2); atomicAdd(&bacc[26], r3);
      atomicAdd(&bacc[27], r4); atomicAdd(&bacc[28], r5); atomicAdd(&bacc[29], r6);
    }
  }
  __syncthreads();
  if (t < BN) {
    float cf = (float)cnt[t];
    Af[0][t] = cf * Af[3][t];
    Af[1][t] = cf * Af[4][t];
    Af[2][t] = cf * Af[5][t];
  }
  __syncthreads();

  const int j0 = lane * 4;
  const float* srow = scores + (size_t)b * BN * BN;
  const int pbase = wave * 32;                 // 32 rows per wave, 2 per group
  const float* wbase = srow + (size_t)pbase * BN + j0;

  // per-lane column accumulators: Tv_d[j] = sum_p (vf*inv*x_d)(p) * E[p][j]
  //                               Tf_d[j] = sum_p (inv*x_d)(p)    * E[p][j]
  float4 Tv0 = {0,0,0,0}, Tv1 = {0,0,0,0}, Tv2 = {0,0,0,0}, Tv3 = {0,0,0,0};
  float4 Tf0 = {0,0,0,0}, Tf1 = {0,0,0,0}, Tf2 = {0,0,0,0}, Tf3 = {0,0,0,0};

  float4 cur0 = *(const float4*)(wbase);
  float4 cur1 = *(const float4*)(wbase + (size_t)BN);

#pragma unroll 1
  for (int g = 0; g < 16; g++) {
    const int gn = (g < 15) ? (g + 1) : 15;   // clamp: last iter re-loads (L1 hit)
    float4 nx0 = *(const float4*)(wbase + (size_t)(2 * gn) * BN);
    float4 nx1 = *(const float4*)(wbase + (size_t)(2 * gn + 1) * BN);

    float4 e0, e1;
    e0.x = __expf(cur0.x); e0.y = __expf(cur0.y); e0.z = __expf(cur0.z); e0.w = __expf(cur0.w);
    e1.x = __expf(cur1.x); e1.y = __expf(cur1.y); e1.z = __expf(cur1.z); e1.w = __expf(cur1.w);
    float s0 = (e0.x + e0.y) + (e0.z + e0.w);
    float s1 = (e1.x + e1.y) + (e1.z + e1.w);
    wred_sum2(s0, s1);
    float inv0 = __builtin_amdgcn_rcpf(s0);
    float inv1 = __builtin_amdgcn_rcpf(s1);

    const int p = pbase + 2 * g;
    {
      float4 kv = *(const float4*)&kxv[p][0];
      float wf1 = inv0 * kv.x, wf2 = inv0 * kv.y, wf3 = inv0 * kv.z;
      float wv0 = kv.w * inv0;
      float wv1 = kv.w * wf1, wv2 = kv.w * wf2, wv3 = kv.w * wf3;
      acc4(Tf0, inv0, e0);
      acc4(Tf1, wf1, e0);
      acc4(Tf2, wf2, e0);
      acc4(Tf3, wf3, e0);
      acc4(Tv0, wv0, e0);
      acc4(Tv1, wv1, e0);
      acc4(Tv2, wv2, e0);
      acc4(Tv3, wv3, e0);
    }
    {
      float4 kv = *(const float4*)&kxv[p + 1][0];
      float wf1 = inv1 * kv.x, wf2 = inv1 * kv.y, wf3 = inv1 * kv.z;
      float wv0 = kv.w * inv1;
      float wv1 = kv.w * wf1, wv2 = kv.w * wf2, wv3 = kv.w * wf3;
      acc4(Tf0, inv1, e1);
      acc4(Tf1, wf1, e1);
      acc4(Tf2, wf2, e1);
      acc4(Tf3, wf3, e1);
      acc4(Tv0, wv0, e1);
      acc4(Tv1, wv1, e1);
      acc4(Tv2, wv2, e1);
      acc4(Tv3, wv3, e1);
    }
    cur0 = nx0; cur1 = nx1;
  }

  // epilogue dots: contract T accumulators with the A columns this lane owns
  float acc[24];
  {
    float4 a6[6];
#pragma unroll
    for (int k = 0; k < 6; k++) a6[k] = *(const float4*)&Af[k][j0];
#pragma unroll
    for (int e = 0; e < 3; e++) {
      acc[0 + e]  = dot4(Tv1, a6[e]);      // P_v row d=0
      acc[3 + e]  = dot4(Tv2, a6[e]);      // P_v row d=1
      acc[6 + e]  = dot4(Tv3, a6[e]);      // P_v row d=2
      acc[9 + e]  = dot4(Tf1, a6[3 + e]);  // P_f row d=0
      acc[12 + e] = dot4(Tf2, a6[3 + e]);  // P_f row d=1
      acc[15 + e] = dot4(Tf3, a6[3 + e]);  // P_f row d=2
      acc[18 + e] = dot4(Tv0, a6[e]);      // Sc
      acc[21 + e] = dot4(Tf0, a6[3 + e]);  // Scf
    }
  }
#pragma unroll
  for (int k = 0; k < 24; k++) {
    float r = wred_sum(acc[k]);
    if (lane == 0) atomicAdd(&bacc[k], r);
  }
  __syncthreads();

  if (t == 0) {
    float M = bacc[30];
    float Minv = 1.f / fmaxf(M, 1.f);
    bool use_v = (M > 3.f);
    const float Ninv = 1.f / (float)BN;
    float H[3][3], mu[3];
#pragma unroll
    for (int d = 0; d < 3; d++) {
      mu[d] = use_v ? bacc[24 + d] * Minv : bacc[27 + d] * Ninv;
#pragma unroll
      for (int e = 0; e < 3; e++) {
        float hv = bacc[d * 3 + e]     - bacc[24 + d] * bacc[18 + e] * Minv;
        float hf = bacc[9 + d * 3 + e] - bacc[27 + d] * bacc[21 + e] * Ninv;
        H[d][e] = use_v ? hv : hf;
      }
    }
    float K[3][3];
#pragma unroll
    for (int i = 0; i < 3; i++)
#pragma unroll
      for (int j = 0; j < 3; j++) {
        float s_ = 0.f;
#pragma unroll
        for (int k = 0; k < 3; k++) s_ += H[k][i] * H[k][j];
        K[i][j] = s_;
      }
    float V[3][3] = {{1.f,0.f,0.f},{0.f,1.f,0.f},{0.f,0.f,1.f}};
    for (int sw = 0; sw < 8; sw++) { jrot<0,1>(K, V); jrot<0,2>(K, V); jrot<1,2>(K, V); }
    float lam[3] = {K[0][0], K[1][1], K[2][2]};
    cswap<0,1>(lam, V); cswap<1,2>(lam, V); cswap<0,1>(lam, V);

    float v1[3] = {V[0][0], V[1][0], V[2][0]};
    float v2[3] = {V[0][1], V[1][1], V[2][1]};
    float v3[3] = {V[0][2], V[1][2], V[2][2]};
    float u1[3], u2[3], u3[3];
#pragma unroll
    for (int i = 0; i < 3; i++) {
      u1[i] = H[i][0] * v1[0] + H[i][1] * v1[1] + H[i][2] * v1[2];
      u2[i] = H[i][0] * v2[0] + H[i][1] * v2[1] + H[i][2] * v2[2];
    }
    float n1s = u1[0]*u1[0] + u1[1]*u1[1] + u1[2]*u1[2];
    if (n1s > 1e-24f) { float r = 1.f / sqrtf(n1s); u1[0]*=r; u1[1]*=r; u1[2]*=r; }
    else { u1[0] = 1.f; u1[1] = 0.f; u1[2] = 0.f; }
    float d12 = u1[0]*u2[0] + u1[1]*u2[1] + u1[2]*u2[2];
    u2[0] -= d12 * u1[0]; u2[1] -= d12 * u1[1]; u2[2] -= d12 * u1[2];
    float n2s = u2[0]*u2[0] + u2[1]*u2[1] + u2[2]*u2[2];
    if (n2s > 1e-24f) { float r = 1.f / sqrtf(n2s); u2[0]*=r; u2[1]*=r; u2[2]*=r; }
    else {
      float ex_ = (fabsf(u1[0]) < 0.9f) ? 1.f : 0.f;
      float ey = 1.f - ex_;
      float cx = u1[1]*0.f - u1[2]*ey;
      float cy = u1[2]*ex_ - u1[0]*0.f;
      float cz = u1[0]*ey - u1[1]*ex_;
      float nn = 1.f / sqrtf(cx*cx + cy*cy + cz*cz + 1e-30f);
      u2[0] = cx*nn; u2[1] = cy*nn; u2[2] = cz*nn;
    }
    u3[0] = u1[1]*u2[2] - u1[2]*u2[1];
    u3[1] = u1[2]*u2[0] - u1[0]*u2[2];
    u3[2] = u1[0]*u2[1] - u1[1]*u2[0];
    float detV = v1[0]*(v2[1]*v3[2] - v2[2]*v3[1])
               - v1[1]*(v2[0]*v3[2] - v2[2]*v3[0])
               + v1[2]*(v2[0]*v3[1] - v2[1]*v3[0]);
    float f = (detV < 0.f) ? -1.f : 1.f;
    float R_[3][3];
#pragma unroll
    for (int i = 0; i < 3; i++)
#pragma unroll
      for (int k = 0; k < 3; k++)
        R_[i][k] = v1[i]*u1[k] + v2[i]*u2[k] + f * v3[i]*u3[k];

    float* Rout = out + (size_t)b * 9;
#pragma unroll
    for (int i = 0; i < 3; i++)
#pragma unroll
      for (int k = 0; k < 3; k++)
        Rout[i * 3 + k] = R_[i][k];
    float* Tout = out + (size_t)gridDim.x * 9 + (size_t)b * 3;
#pragma unroll
    for (int i = 0; i < 3; i++)
      Tout[i] = -(R_[i][0]*mu[0] + R_[i][1]*mu[1] + R_[i][2]*mu[2]);
  }
}

extern "C" void kernel_launch(void* const* d_in, const int* in_sizes, int n_in,
                              void* d_out, int out_size, void* d_ws, size_t ws_size,
                              hipStream_t stream) {
  const float* src = (const float*)d_in[0];
  const float* tgt = (const float*)d_in[1];
  const float* scores = (const float*)d_in[2];
  const int* idx0 = (const int*)d_in[3];
  float* out = (float*)d_out;
  int B = in_sizes[0] / (3 * BN);
  hipLaunchKernelGGL(svdhead_kernel, dim3(B), dim3(BLOCK), 0, stream,
                     src, tgt, scores, idx0, out);
}

// Round 7
// 53.165 us; speedup vs baseline: 10.5177x; 1.0557x over previous
//
#include <hip/hip_runtime.h>
#include <math.h>

#define BN 256
#define BLOCK 512

__device__ __forceinline__ float wred_sum(float v) {
#pragma unroll
  for (int m = 32; m >= 1; m >>= 1) v += __shfl_xor(v, m, 64);
  return v;
}

template<int P, int Q>
__device__ __forceinline__ void jrot(float K[3][3], float V[3][3]) {
  float apq = K[P][Q];
  if (apq == 0.f) return;
  float app = K[P][P], aqq = K[Q][Q];
  float tau = (aqq - app) / (2.f * apq);
  float st = sqrtf(1.f + tau * tau);
  float tt = (tau >= 0.f) ? 1.f / (tau + st) : 1.f / (tau - st);
  float c = 1.f / sqrtf(1.f + tt * tt);
  float s = tt * c;
#pragma unroll
  for (int k = 0; k < 3; k++) { float kp = K[k][P], kq = K[k][Q]; K[k][P] = c * kp - s * kq; K[k][Q] = s * kp + c * kq; }
#pragma unroll
  for (int k = 0; k < 3; k++) { float kp = K[P][k], kq = K[Q][k]; K[P][k] = c * kp - s * kq; K[Q][k] = s * kp + c * kq; }
#pragma unroll
  for (int k = 0; k < 3; k++) { float vp = V[k][P], vq = V[k][Q]; V[k][P] = c * vp - s * vq; V[k][Q] = s * vp + c * vq; }
}

template<int A, int C>
__device__ __forceinline__ void cswap(float lam[3], float V[3][3]) {
  if (lam[A] < lam[C]) {
    float tl = lam[A]; lam[A] = lam[C]; lam[C] = tl;
#pragma unroll
    for (int k = 0; k < 3; k++) { float tv = V[k][A]; V[k][A] = V[k][C]; V[k][C] = tv; }
  }
}

__device__ __forceinline__ void acc4(float4& T, float s, const float4& e) {
  T.x += s * e.x; T.y += s * e.y; T.z += s * e.z; T.w += s * e.w;
}

__device__ __forceinline__ float dot4(const float4& a, const float4& b) {
  return a.x * b.x + a.y * b.y + a.z * b.z + a.w * b.w;
}

extern "C" __global__ void __launch_bounds__(BLOCK, 2)
svdhead_kernel(const float* __restrict__ src,
               const float* __restrict__ tgt,
               const float* __restrict__ scores,
               const int* __restrict__ idx0,
               float* __restrict__ out)
{
  __shared__ __align__(16) float Af[6][BN];   // [0..2]=count*kpts1_d, [3..5]=kpts1_d
  __shared__ __align__(16) float kxv[BN][4];  // {x0, x1, x2, vf} per row
  __shared__ int cnt[BN];
  __shared__ float bacc[31];  // 0..8 P_v, 9..17 P_f, 18..20 Sc, 21..23 Scf, 24..26 Sxv, 27..29 Sxf, 30 M

  const int t = threadIdx.x;
  const int b = blockIdx.x;
  const int lane = t & 63;
  const int wave = t >> 6;

  if (t < 31) bacc[t] = 0.f;
  if (t < BN) cnt[t] = 0;
  __syncthreads();

  float x0 = 0.f, x1 = 0.f, x2 = 0.f, vf = 0.f;
  if (t < BN) {
    int id = idx0[(size_t)b * BN + t];        // values in [0,256]; 256 == SENTINEL
    int valid = ((unsigned)id < 256u);
    vf = valid ? 1.f : 0.f;
    if (valid) atomicAdd(&cnt[id], 1);
    const float* sb = src + (size_t)b * 3 * BN;
    const float* tb = tgt + (size_t)b * 3 * BN;
    x0 = sb[t]; x1 = sb[BN + t]; x2 = sb[2 * BN + t];
    kxv[t][0] = x0; kxv[t][1] = x1; kxv[t][2] = x2; kxv[t][3] = vf;
    Af[3][t] = tb[t]; Af[4][t] = tb[BN + t]; Af[5][t] = tb[2 * BN + t];
  }
  {
    float r0 = wred_sum(vf);
    float r1 = wred_sum(vf * x0);
    float r2 = wred_sum(vf * x1);
    float r3 = wred_sum(vf * x2);
    float r4 = wred_sum(x0);
    float r5 = wred_sum(x1);
    float r6 = wred_sum(x2);
    if (lane == 0) {
      atomicAdd(&bacc[30], r0);
      atomicAdd(&bacc[24], r1); atomicAdd(&bacc[25], r2); atomicAdd(&bacc[26], r3);
      atomicAdd(&bacc[27], r4); atomicAdd(&bacc[28], r5); atomicAdd(&bacc[29], r6);
    }
  }
  __syncthreads();
  if (t < BN) {
    float cf = (float)cnt[t];
    Af[0][t] = cf * Af[3][t];
    Af[1][t] = cf * Af[4][t];
    Af[2][t] = cf * Af[5][t];
  }
  __syncthreads();

  const int j0 = lane * 4;
  const float* srow = scores + (size_t)b * BN * BN;
  const int pbase = wave * 32;                 // 32 rows per wave, 8 per batch
  const float* wbase = srow + (size_t)pbase * BN + j0;

  // per-lane column accumulators
  float4 Tv0 = {0,0,0,0}, Tv1 = {0,0,0,0}, Tv2 = {0,0,0,0}, Tv3 = {0,0,0,0};
  float4 Tf0 = {0,0,0,0}, Tf1 = {0,0,0,0}, Tf2 = {0,0,0,0}, Tf3 = {0,0,0,0};

  float4 cur[8];
#pragma unroll
  for (int r = 0; r < 8; r++) cur[r] = *(const float4*)(wbase + (size_t)r * BN);

#pragma unroll 1
  for (int g = 0; g < 4; g++) {
    const int gn = (g < 3) ? (g + 1) : 3;     // clamp: last iter re-loads (cache hit)
    float4 nx[8];
#pragma unroll
    for (int r = 0; r < 8; r++)
      nx[r] = *(const float4*)(wbase + (size_t)(8 * gn + r) * BN);

    // exp in place + per-lane partial sums
    float s[8];
#pragma unroll
    for (int r = 0; r < 8; r++) {
      cur[r].x = __expf(cur[r].x); cur[r].y = __expf(cur[r].y);
      cur[r].z = __expf(cur[r].z); cur[r].w = __expf(cur[r].w);
      s[r] = (cur[r].x + cur[r].y) + (cur[r].z + cur[r].w);
    }
    // 8 interleaved 64-lane butterflies (ILP-8 on the DS chain)
#pragma unroll
    for (int m = 32; m >= 1; m >>= 1) {
#pragma unroll
      for (int r = 0; r < 8; r++) s[r] += __shfl_xor(s[r], m, 64);
    }
#pragma unroll
    for (int r = 0; r < 8; r++) {
      float inv = __builtin_amdgcn_rcpf(s[r]);
      float4 kv = *(const float4*)&kxv[pbase + 8 * g + r][0];
      float wf1 = inv * kv.x, wf2 = inv * kv.y, wf3 = inv * kv.z;
      float wv0 = kv.w * inv;
      float wv1 = kv.w * wf1, wv2 = kv.w * wf2, wv3 = kv.w * wf3;
      acc4(Tf0, inv, cur[r]);
      acc4(Tf1, wf1, cur[r]);
      acc4(Tf2, wf2, cur[r]);
      acc4(Tf3, wf3, cur[r]);
      acc4(Tv0, wv0, cur[r]);
      acc4(Tv1, wv1, cur[r]);
      acc4(Tv2, wv2, cur[r]);
      acc4(Tv3, wv3, cur[r]);
    }
#pragma unroll
    for (int r = 0; r < 8; r++) cur[r] = nx[r];
  }

  // epilogue dots: contract T accumulators with the A columns this lane owns
  float acc[24];
  {
    float4 a6[6];
#pragma unroll
    for (int k = 0; k < 6; k++) a6[k] = *(const float4*)&Af[k][j0];
#pragma unroll
    for (int e = 0; e < 3; e++) {
      acc[0 + e]  = dot4(Tv1, a6[e]);      // P_v row d=0
      acc[3 + e]  = dot4(Tv2, a6[e]);      // P_v row d=1
      acc[6 + e]  = dot4(Tv3, a6[e]);      // P_v row d=2
      acc[9 + e]  = dot4(Tf1, a6[3 + e]);  // P_f row d=0
      acc[12 + e] = dot4(Tf2, a6[3 + e]);  // P_f row d=1
      acc[15 + e] = dot4(Tf3, a6[3 + e]);  // P_f row d=2
      acc[18 + e] = dot4(Tv0, a6[e]);      // Sc
      acc[21 + e] = dot4(Tf0, a6[3 + e]);  // Scf
    }
  }
#pragma unroll
  for (int k = 0; k < 24; k++) {
    float r = wred_sum(acc[k]);
    if (lane == 0) atomicAdd(&bacc[k], r);
  }
  __syncthreads();

  if (t == 0) {
    float M = bacc[30];
    float Minv = 1.f / fmaxf(M, 1.f);
    bool use_v = (M > 3.f);
    const float Ninv = 1.f / (float)BN;
    float H[3][3], mu[3];
#pragma unroll
    for (int d = 0; d < 3; d++) {
      mu[d] = use_v ? bacc[24 + d] * Minv : bacc[27 + d] * Ninv;
#pragma unroll
      for (int e = 0; e < 3; e++) {
        float hv = bacc[d * 3 + e]     - bacc[24 + d] * bacc[18 + e] * Minv;
        float hf = bacc[9 + d * 3 + e] - bacc[27 + d] * bacc[21 + e] * Ninv;
        H[d][e] = use_v ? hv : hf;
      }
    }
    float K[3][3];
#pragma unroll
    for (int i = 0; i < 3; i++)
#pragma unroll
      for (int j = 0; j < 3; j++) {
        float s_ = 0.f;
#pragma unroll
        for (int k = 0; k < 3; k++) s_ += H[k][i] * H[k][j];
        K[i][j] = s_;
      }
    float V[3][3] = {{1.f,0.f,0.f},{0.f,1.f,0.f},{0.f,0.f,1.f}};
    for (int sw = 0; sw < 8; sw++) { jrot<0,1>(K, V); jrot<0,2>(K, V); jrot<1,2>(K, V); }
    float lam[3] = {K[0][0], K[1][1], K[2][2]};
    cswap<0,1>(lam, V); cswap<1,2>(lam, V); cswap<0,1>(lam, V);

    float v1[3] = {V[0][0], V[1][0], V[2][0]};
    float v2[3] = {V[0][1], V[1][1], V[2][1]};
    float v3[3] = {V[0][2], V[1][2], V[2][2]};
    float u1[3], u2[3], u3[3];
#pragma unroll
    for (int i = 0; i < 3; i++) {
      u1[i] = H[i][0] * v1[0] + H[i][1] * v1[1] + H[i][2] * v1[2];
      u2[i] = H[i][0] * v2[0] + H[i][1] * v2[1] + H[i][2] * v2[2];
    }
    float n1s = u1[0]*u1[0] + u1[1]*u1[1] + u1[2]*u1[2];
    if (n1s > 1e-24f) { float r = 1.f / sqrtf(n1s); u1[0]*=r; u1[1]*=r; u1[2]*=r; }
    else { u1[0] = 1.f; u1[1] = 0.f; u1[2] = 0.f; }
    float d12 = u1[0]*u2[0] + u1[1]*u2[1] + u1[2]*u2[2];
    u2[0] -= d12 * u1[0]; u2[1] -= d12 * u1[1]; u2[2] -= d12 * u1[2];
    float n2s = u2[0]*u2[0] + u2[1]*u2[1] + u2[2]*u2[2];
    if (n2s > 1e-24f) { float r = 1.f / sqrtf(n2s); u2[0]*=r; u2[1]*=r; u2[2]*=r; }
    else {
      float ex_ = (fabsf(u1[0]) < 0.9f) ? 1.f : 0.f;
      float ey = 1.f - ex_;
      float cx = u1[1]*0.f - u1[2]*ey;
      float cy = u1[2]*ex_ - u1[0]*0.f;
      float cz = u1[0]*ey - u1[1]*ex_;
      float nn = 1.f / sqrtf(cx*cx + cy*cy + cz*cz + 1e-30f);
      u2[0] = cx*nn; u2[1] = cy*nn; u2[2] = cz*nn;
    }
    u3[0] = u1[1]*u2[2] - u1[2]*u2[1];
    u3[1] = u1[2]*u2[0] - u1[0]*u2[2];
    u3[2] = u1[0]*u2[1] - u1[1]*u2[0];
    float detV = v1[0]*(v2[1]*v3[2] - v2[2]*v3[1])
               - v1[1]*(v2[0]*v3[2] - v2[2]*v3[0])
               + v1[2]*(v2[0]*v3[1] - v2[1]*v3[0]);
    float f = (detV < 0.f) ? -1.f : 1.f;
    float R_[3][3];
#pragma unroll
    for (int i = 0; i < 3; i++)
#pragma unroll
      for (int k = 0; k < 3; k++)
        R_[i][k] = v1[i]*u1[k] + v2[i]*u2[k] + f * v3[i]*u3[k];

    float* Rout = out + (size_t)b * 9;
#pragma unroll
    for (int i = 0; i < 3; i++)
#pragma unroll
      for (int k = 0; k < 3; k++)
        Rout[i * 3 + k] = R_[i][k];
    float* Tout = out + (size_t)gridDim.x * 9 + (size_t)b * 3;
#pragma unroll
    for (int i = 0; i < 3; i++)
      Tout[i] = -(R_[i][0]*mu[0] + R_[i][1]*mu[1] + R_[i][2]*mu[2]);
  }
}

extern "C" void kernel_launch(void* const* d_in, const int* in_sizes, int n_in,
                              void* d_out, int out_size, void* d_ws, size_t ws_size,
                              hipStream_t stream) {
  const float* src = (const float*)d_in[0];
  const float* tgt = (const float*)d_in[1];
  const float* scores = (const float*)d_in[2];
  const int* idx0 = (const int*)d_in[3];
  float* out = (float*)d_out;
  int B = in_sizes[0] / (3 * BN);
  hipLaunchKernelGGL(svdhead_kernel, dim3(B), dim3(BLOCK), 0, stream,
                     src, tgt, scores, idx0, out);
}